// Round 8
// baseline (256.380 us; speedup 1.0000x reference)
//
#include <hip/hip_runtime.h>
#include <math.h>

#define Bn 8
#define Cc 512
#define HW 1024
#define HEADS 8
#define HD 64
#define GROUPS 32
#define CPG 16
#define EPS 1e-5f

// DIAGNOSTIC BUILD: each phase kernel repeats its body REPS times so every phase
// dispatch exceeds the harness's 43us fill dispatches and surfaces in rocprof top-5.
// Phases are idempotent; rep 2 re-zeros accumulators and is the final writer.
#define REPS 2

// Counted-wait primitives (T3/T4): loads stay in flight across barriers.
#define VMW8()  asm volatile("s_waitcnt vmcnt(8)" ::: "memory")
#define VMW6()  asm volatile("s_waitcnt vmcnt(6)" ::: "memory")
#define VMW0()  asm volatile("s_waitcnt vmcnt(0)" ::: "memory")
#define LGKM0() asm volatile("s_waitcnt lgkmcnt(0)" ::: "memory")
#define SB()    __builtin_amdgcn_s_barrier()
#define SCHED0() __builtin_amdgcn_sched_barrier(0)

typedef float f32x4 __attribute__((ext_vector_type(4)));
typedef __bf16 bf16x8 __attribute__((ext_vector_type(8)));
typedef __bf16 bf16x4 __attribute__((ext_vector_type(4)));
typedef short s16x4 __attribute__((ext_vector_type(4)));
typedef unsigned u32x2 __attribute__((ext_vector_type(2)));

__device__ __forceinline__ void async16(const __bf16* g, __bf16* l) {
    __builtin_amdgcn_global_load_lds((const __attribute__((address_space(1))) unsigned int*)g,
                                     (__attribute__((address_space(3))) unsigned int*)l, 16, 0, 0);
}

__device__ __forceinline__ f32x4 mfma16(bf16x4 a, bf16x4 b, f32x4 c) {
    return __builtin_amdgcn_mfma_f32_16x16x16bf16_1k(
        __builtin_bit_cast(s16x4, a), __builtin_bit_cast(s16x4, b), c, 0, 0, 0);
}

__device__ __forceinline__ unsigned pk_bf16(float f1, float f0) {
    return __builtin_amdgcn_perm(__builtin_bit_cast(unsigned, f1),
                                 __builtin_bit_cast(unsigned, f0), 0x07060302u);
}

// ---------------- Phase 1: GN (blk<256) + weight conv (blk in [256,768)) ----------------
__device__ __forceinline__ void gn_phase(char* smem, int blk, int tid,
    const float* __restrict__ x, const float* __restrict__ gamma,
    const float* __restrict__ beta, __bf16* __restrict__ hnT,
    const float* __restrict__ wq, __bf16* __restrict__ wq_bf,
    const float* __restrict__ wp, __bf16* __restrict__ wp_bf) {
    if (blk >= 256) {
        int base = (blk - 256) * 512 + tid;
        #pragma unroll
        for (int u = 0; u < 2; ++u) {
            int i = base + u * 256;
            if (i < 196608) {
                float4 v = ((const float4*)wq)[i];
                bf16x4 o = { (__bf16)v.x, (__bf16)v.y, (__bf16)v.z, (__bf16)v.w };
                ((bf16x4*)wq_bf)[i] = o;
            } else {
                int j = i - 196608;
                float4 v = ((const float4*)wp)[j];
                bf16x4 o = { (__bf16)v.x, (__bf16)v.y, (__bf16)v.z, (__bf16)v.w };
                ((bf16x4*)wp_bf)[j] = o;
            }
        }
        return;
    }
    __bf16* xs = (__bf16*)smem;          // full 32 KB
    float* fs = (float*)smem;            // overlay: fs[0..9] used transiently
    int b = blk >> 5, g = blk & 31;
    const float* xp = x + ((size_t)b * Cc + g * CPG) * HW;

    float s = 0.f, ss = 0.f;
    for (int i4 = tid; i4 < 4096; i4 += 256) {
        float4 v = ((const float4*)xp)[i4];
        s  += (v.x + v.y) + (v.z + v.w);
        ss += (v.x * v.x + v.y * v.y) + (v.z * v.z + v.w * v.w);
        bf16x4 o = { (__bf16)v.x, (__bf16)v.y, (__bf16)v.z, (__bf16)v.w };
        ((bf16x4*)xs)[i4] = o;
    }
    for (int off = 32; off > 0; off >>= 1) {
        s  += __shfl_down(s, off);
        ss += __shfl_down(ss, off);
    }
    int wave = tid >> 6, lane = tid & 63;
    __syncthreads();                      // staging complete
    float keep = 0.f;
    if (tid < 20) keep = (float)xs[tid];  // preserve c=0, n=0..19 (lossless bf16 round-trip)
    __syncthreads();                      // reads done before overlay write
    if (lane == 0) { fs[wave * 2] = s; fs[wave * 2 + 1] = ss; }
    __syncthreads();
    if (tid == 0) {
        float S  = fs[0] + fs[2] + fs[4] + fs[6];
        float SS = fs[1] + fs[3] + fs[5] + fs[7];
        float mean = S / 16384.f;
        float var  = SS / 16384.f - mean * mean;
        fs[8] = mean;
        fs[9] = rsqrtf(var + EPS);
    }
    __syncthreads();
    float mean = fs[8], rstd = fs[9];
    __syncthreads();                      // all read stats before restore
    if (tid < 20) xs[tid] = (__bf16)keep; // restore xs
    __syncthreads();

    float gl[16], bl[16];                 // uniform -> scalar loads
    #pragma unroll
    for (int c = 0; c < 16; ++c) { gl[c] = gamma[g * CPG + c]; bl[c] = beta[g * CPG + c]; }
    #pragma unroll
    for (int u = 0; u < 4; ++u) {
        int n = tid + u * 256;
        union { __bf16 bs[16]; uint4 q[2]; } o;
        #pragma unroll
        for (int c = 0; c < 16; ++c) {
            float v = (float)xs[c * 1024 + n];
            o.bs[c] = (__bf16)((v - mean) * rstd * gl[c] + bl[c]);
        }
        uint4* dst = (uint4*)(hnT + ((size_t)b * HW + n) * Cc + g * CPG);
        dst[0] = o.q[0];
        dst[1] = o.q[1];
    }
}

// ---------------- Phase 2: one 128x128 QKV tile, counted-vmcnt pipeline ----------------
__device__ __forceinline__ void qkv_stage(char* base, int tid,
    const __bf16* __restrict__ Pb, const __bf16* __restrict__ Qb,
    int bm, int bn, int k0) {
    __bf16* As = (__bf16*)base;
    __bf16* Bs = (__bf16*)(base + 16384);
    #pragma unroll
    for (int u = 0; u < 4; ++u) {
        int idx = u * 256 + tid;
        int r = idx >> 3, lc = idx & 7;
        int cg2 = lc ^ (r & 7);
        async16(Pb + (size_t)(bm + r) * 512 + k0 + cg2 * 8, &As[idx * 8]);
        async16(Qb + (size_t)(bn + r) * 512 + k0 + cg2 * 8, &Bs[idx * 8]);
    }
}

__device__ __forceinline__ void qkv_tile(char* smem, int t, int tid,
    const __bf16* __restrict__ hnT, const __bf16* __restrict__ wq,
    const float* __restrict__ bias, __bf16* __restrict__ qkT,
    __bf16* __restrict__ vbuf, float scaleLo) {
    int wv = tid >> 6, lane = tid & 63, ln = lane & 15, quad = lane >> 4;
    int b = t / 96, rem = t % 96;
    int y = rem >> 3, xv = rem & 7;
    bool isQK = y < 8;
    int bm = (isQK ? y : y - 8) * 128;
    int bn = xv * 128;
    const __bf16* hb = hnT + (size_t)b * HW * Cc;
    const __bf16* Pb = isQK ? hb : wq + (size_t)1024 * 512;
    const __bf16* Qb = isQK ? wq : hb;
    int wm = (wv >> 1) * 64, wn = (wv & 1) * 64;

    f32x4 acc[4][4];
    #pragma unroll
    for (int i = 0; i < 4; ++i)
        #pragma unroll
        for (int j = 0; j < 4; ++j) acc[i][j] = (f32x4){0.f, 0.f, 0.f, 0.f};

    char* sm_cur = smem;
    char* sm_nxt = smem + 32768;

    qkv_stage(sm_cur, tid, Pb, Qb, bm, bn, 0);       // prologue: 8 loads/thread in flight

    for (int kt = 0; kt < 8; ++kt) {
        if (kt < 7) {
            qkv_stage(sm_nxt, tid, Pb, Qb, bm, bn, (kt + 1) * 64);  // +8 loads (next tile)
            VMW8();                                   // wait CUR's 8 (older); NXT's 8 stay in flight
        } else {
            VMW0();
        }
        SB(); SCHED0();                               // all waves: cur tile resident

        __bf16* As = (__bf16*)sm_cur;
        __bf16* Bs = (__bf16*)(sm_cur + 16384);
        bf16x8 af[4][2], bff[4][2];
        #pragma unroll
        for (int mt = 0; mt < 4; ++mt) {
            int row = wm + mt * 16 + ln;
            #pragma unroll
            for (int h = 0; h < 2; ++h) {
                int cc = (h * 4 + quad) ^ (ln & 7);
                af[mt][h] = *(const bf16x8*)&As[row * 64 + cc * 8];
            }
        }
        #pragma unroll
        for (int nt = 0; nt < 4; ++nt) {
            int row = wn + nt * 16 + ln;
            #pragma unroll
            for (int h = 0; h < 2; ++h) {
                int cc = (h * 4 + quad) ^ (ln & 7);
                bff[nt][h] = *(const bf16x8*)&Bs[row * 64 + cc * 8];
            }
        }
        #pragma unroll
        for (int mt = 0; mt < 4; ++mt)
            #pragma unroll
            for (int nt = 0; nt < 4; ++nt) {
                acc[mt][nt] = __builtin_amdgcn_mfma_f32_16x16x32_bf16(af[mt][0], bff[nt][0], acc[mt][nt], 0, 0, 0);
                acc[mt][nt] = __builtin_amdgcn_mfma_f32_16x16x32_bf16(af[mt][1], bff[nt][1], acc[mt][nt], 0, 0, 0);
            }
        if (kt < 7) {
            LGKM0(); SB(); SCHED0();                  // all reads of cur done -> overwrite ok
        }
        char* tmp = sm_cur; sm_cur = sm_nxt; sm_nxt = tmp;
    }

    if (isQK) {
        __bf16* out = qkT + (size_t)b * HW * 1024;
        float bcol[4], scol[4];
        #pragma unroll
        for (int nt = 0; nt < 4; ++nt) {
            int col = bn + wn + nt * 16 + ln;
            bcol[nt] = bias[col];
            scol[nt] = (col < 512) ? scaleLo : 1.0f;
        }
        #pragma unroll
        for (int mt = 0; mt < 4; ++mt)
            #pragma unroll
            for (int r = 0; r < 4; ++r) {
                int row = bm + wm + mt * 16 + quad * 4 + r;
                #pragma unroll
                for (int nt = 0; nt < 4; ++nt) {
                    int col = bn + wn + nt * 16 + ln;
                    out[(size_t)row * 1024 + col] = (__bf16)((acc[mt][nt][r] + bcol[nt]) * scol[nt]);
                }
            }
    } else {
        __bf16* out = vbuf + (size_t)b * Cc * HW;
        #pragma unroll
        for (int mt = 0; mt < 4; ++mt)
            #pragma unroll
            for (int r = 0; r < 4; ++r) {
                int row = bm + wm + mt * 16 + quad * 4 + r;
                float brow = bias[1024 + row];
                #pragma unroll
                for (int nt = 0; nt < 4; ++nt) {
                    int col = bn + wn + nt * 16 + ln;
                    out[(size_t)row * 1024 + col] = (__bf16)(acc[mt][nt][r] + brow);
                }
            }
    }
}

// ---------------- Phase 3: flash attention, counted-vmcnt K/V pipeline ----------------
__device__ __forceinline__ void attn_stage(char* base, int tid,
    const __bf16* __restrict__ qkT, const __bf16* __restrict__ vbuf,
    int b, int h, int kt) {
    __bf16* Ks = (__bf16*)base;
    __bf16* Vs = (__bf16*)(base + 16384);
    #pragma unroll
    for (int hh = 0; hh < 2; ++hh) {
        int kb = kt * 128 + hh * 64;
        #pragma unroll
        for (int u = 0; u < 2; ++u) {
            int idx = u * 256 + tid;
            int r = idx >> 3, lc = idx & 7;
            int cg2 = lc ^ (r & 7);
            async16(qkT + ((size_t)b * HW + kb + r) * 1024 + 512 + h * HD + cg2 * 8,
                    &Ks[hh * 4096 + idx * 8]);
            async16(vbuf + ((size_t)b * Cc + h * HD + r) * HW + kb + cg2 * 8,
                    &Vs[hh * 4096 + idx * 8]);
        }
    }
}

__device__ __forceinline__ void attn_unit(char* smem, int blk, int tid,
    const __bf16* __restrict__ qkT, const __bf16* __restrict__ vbuf,
    __bf16* __restrict__ attnT) {
    int wv = tid >> 6, lane = tid & 63, ln = lane & 15, quad = lane >> 4;
    int h = blk & 7, qb = (blk >> 3) & 7, b = blk >> 6;
    int i0 = qb * 128 + wv * 32;

    const __bf16* qbase = qkT + ((size_t)b * HW + i0 + ln) * 1024 + h * HD + quad * 8;
    bf16x8 qf[2][2];
    #pragma unroll
    for (int mt = 0; mt < 2; ++mt) {
        qf[mt][0] = *(const bf16x8*)(qbase + (size_t)mt * 16 * 1024);
        qf[mt][1] = *(const bf16x8*)(qbase + (size_t)mt * 16 * 1024 + 32);
    }

    f32x4 oacc[2][4];
    #pragma unroll
    for (int mt = 0; mt < 2; ++mt)
        #pragma unroll
        for (int ct = 0; ct < 4; ++ct) oacc[mt][ct] = (f32x4){0.f, 0.f, 0.f, 0.f};
    float lsum[2] = {0.f, 0.f};

    char* sm_cur = smem;
    char* sm_nxt = smem + 32768;
    attn_stage(sm_cur, tid, qkT, vbuf, b, h, 0);     // prologue: 8 loads/thread

    for (int kt = 0; kt < 8; ++kt) {
        if (kt < 7) {
            attn_stage(sm_nxt, tid, qkT, vbuf, b, h, kt + 1);   // +8 loads
            VMW8();
        } else {
            VMW0();
        }
        SB(); SCHED0();

        __bf16* Ks = (__bf16*)sm_cur;
        __bf16* Vs = (__bf16*)(sm_cur + 16384);

        #pragma unroll
        for (int hh = 0; hh < 2; ++hh) {
            f32x4 st[2][4];
            #pragma unroll
            for (int jt = 0; jt < 4; ++jt) {
                int row = jt * 16 + ln;
                int c0 = quad ^ (ln & 7);
                int c1 = (4 + quad) ^ (ln & 7);
                bf16x8 kf0 = *(const bf16x8*)&Ks[hh * 4096 + row * 64 + c0 * 8];
                bf16x8 kf1 = *(const bf16x8*)&Ks[hh * 4096 + row * 64 + c1 * 8];
                #pragma unroll
                for (int mt = 0; mt < 2; ++mt) {
                    f32x4 s = (f32x4){0.f, 0.f, 0.f, 0.f};
                    s = __builtin_amdgcn_mfma_f32_16x16x32_bf16(kf0, qf[mt][0], s, 0, 0, 0);
                    s = __builtin_amdgcn_mfma_f32_16x16x32_bf16(kf1, qf[mt][1], s, 0, 0, 0);
                    st[mt][jt] = s;
                }
            }

            bf16x4 pk[2][4];
            #pragma unroll
            for (int mt = 0; mt < 2; ++mt)
                #pragma unroll
                for (int jt = 0; jt < 4; ++jt) {
                    float p0 = __builtin_amdgcn_exp2f(st[mt][jt][0]);
                    float p1 = __builtin_amdgcn_exp2f(st[mt][jt][1]);
                    float p2 = __builtin_amdgcn_exp2f(st[mt][jt][2]);
                    float p3 = __builtin_amdgcn_exp2f(st[mt][jt][3]);
                    lsum[mt] += (p0 + p1) + (p2 + p3);
                    u32x2 w = { pk_bf16(p1, p0), pk_bf16(p3, p2) };
                    pk[mt][jt] = __builtin_bit_cast(bf16x4, w);
                }

            #pragma unroll
            for (int ct = 0; ct < 4; ++ct) {
                int row = ct * 16 + ln;
                bf16x4 vf[4];
                #pragma unroll
                for (int kss = 0; kss < 4; ++kss) {
                    int cc16 = (kss * 2 + (quad >> 1)) ^ (ln & 7);
                    vf[kss] = *(const bf16x4*)&Vs[hh * 4096 + row * 64 + cc16 * 8 + (quad & 1) * 4];
                }
                #pragma unroll
                for (int mt = 0; mt < 2; ++mt)
                    #pragma unroll
                    for (int kss = 0; kss < 4; ++kss)
                        oacc[mt][ct] = mfma16(vf[kss], pk[mt][kss], oacc[mt][ct]);
            }
        }
        if (kt < 7) {
            LGKM0(); SB(); SCHED0();
        }
        char* tmp = sm_cur; sm_cur = sm_nxt; sm_nxt = tmp;
    }

    #pragma unroll
    for (int mt = 0; mt < 2; ++mt) {
        lsum[mt] += __shfl_xor(lsum[mt], 16);
        lsum[mt] += __shfl_xor(lsum[mt], 32);
        float rl = 1.f / lsum[mt];
        __bf16* op = attnT + ((size_t)b * HW + i0 + mt * 16 + ln) * Cc + h * HD + quad * 4;
        #pragma unroll
        for (int ct = 0; ct < 4; ++ct) {
            bf16x4 o = { (__bf16)(oacc[mt][ct][0] * rl), (__bf16)(oacc[mt][ct][1] * rl),
                         (__bf16)(oacc[mt][ct][2] * rl), (__bf16)(oacc[mt][ct][3] * rl) };
            *(bf16x4*)(op + ct * 16) = o;
        }
    }
}

// ---------------- Phase 4: proj 64x128 tile, counted-vmcnt pipeline ----------------
__device__ __forceinline__ void proj_stage(char* base, int tid,
    const __bf16* __restrict__ wp, const __bf16* __restrict__ Qb,
    int bm, int bn, int k0) {
    __bf16* As = (__bf16*)base;
    __bf16* Bs = (__bf16*)(base + 8192);
    #pragma unroll
    for (int u = 0; u < 2; ++u) {
        int idx = u * 256 + tid;
        int r = idx >> 3, lc = idx & 7;
        int cg2 = lc ^ (r & 7);
        async16(wp + (size_t)(bm + r) * 512 + k0 + cg2 * 8, &As[idx * 8]);
    }
    #pragma unroll
    for (int u = 0; u < 4; ++u) {
        int idx = u * 256 + tid;
        int r = idx >> 3, lc = idx & 7;
        int cg2 = lc ^ (r & 7);
        async16(Qb + (size_t)(bn + r) * 512 + k0 + cg2 * 8, &Bs[idx * 8]);
    }
}

__device__ __forceinline__ void proj_unit(char* smem, int blk, int tid,
    const __bf16* __restrict__ wp, const __bf16* __restrict__ attnT,
    const float* __restrict__ bias, const float* __restrict__ resid,
    float* __restrict__ outp) {
    int wv = tid >> 6, lane = tid & 63, ln = lane & 15, quad = lane >> 4;
    int xv = blk & 7, y = (blk >> 3) & 7, b = blk >> 6;
    int bm = y * 64, bn = xv * 128;
    const __bf16* Qb = attnT + (size_t)b * HW * Cc;
    int wm = (wv >> 1) * 32, wn = (wv & 1) * 64;

    f32x4 acc[2][4];
    #pragma unroll
    for (int i = 0; i < 2; ++i)
        #pragma unroll
        for (int j = 0; j < 4; ++j) acc[i][j] = (f32x4){0.f, 0.f, 0.f, 0.f};

    char* sm_cur = smem;
    char* sm_nxt = smem + 24576;
    proj_stage(sm_cur, tid, wp, Qb, bm, bn, 0);      // prologue: 6 loads/thread

    for (int kt = 0; kt < 8; ++kt) {
        if (kt < 7) {
            proj_stage(sm_nxt, tid, wp, Qb, bm, bn, (kt + 1) * 64);  // +6 loads
            VMW6();
        } else {
            VMW0();
        }
        SB(); SCHED0();

        __bf16* As = (__bf16*)sm_cur;
        __bf16* Bs = (__bf16*)(sm_cur + 8192);
        bf16x8 af[2][2], bff[4][2];
        #pragma unroll
        for (int mt = 0; mt < 2; ++mt) {
            int row = wm + mt * 16 + ln;
            #pragma unroll
            for (int h = 0; h < 2; ++h) {
                int cc = (h * 4 + quad) ^ (ln & 7);
                af[mt][h] = *(const bf16x8*)&As[row * 64 + cc * 8];
            }
        }
        #pragma unroll
        for (int nt = 0; nt < 4; ++nt) {
            int row = wn + nt * 16 + ln;
            #pragma unroll
            for (int h = 0; h < 2; ++h) {
                int cc = (h * 4 + quad) ^ (ln & 7);
                bff[nt][h] = *(const bf16x8*)&Bs[row * 64 + cc * 8];
            }
        }
        #pragma unroll
        for (int mt = 0; mt < 2; ++mt)
            #pragma unroll
            for (int nt = 0; nt < 4; ++nt) {
                acc[mt][nt] = __builtin_amdgcn_mfma_f32_16x16x32_bf16(af[mt][0], bff[nt][0], acc[mt][nt], 0, 0, 0);
                acc[mt][nt] = __builtin_amdgcn_mfma_f32_16x16x32_bf16(af[mt][1], bff[nt][1], acc[mt][nt], 0, 0, 0);
            }
        if (kt < 7) {
            LGKM0(); SB(); SCHED0();
        }
        char* tmp = sm_cur; sm_cur = sm_nxt; sm_nxt = tmp;
    }

    float* out = outp + (size_t)b * Cc * HW;
    const float* res = resid + (size_t)b * Cc * HW;
    #pragma unroll
    for (int mt = 0; mt < 2; ++mt)
        #pragma unroll
        for (int r = 0; r < 4; ++r) {
            int row = bm + wm + mt * 16 + quad * 4 + r;
            float bv = bias[row];
            #pragma unroll
            for (int nt = 0; nt < 4; ++nt) {
                int col = bn + wn + nt * 16 + ln;
                size_t idx = (size_t)row * 1024 + col;
                out[idx] = acc[mt][nt][r] + bv + res[idx];
            }
        }
}

// ---------------- Phase kernels (4 regular launches, REPS-fold diagnostic repeat) --------
__global__ __launch_bounds__(256, 3) void gn_k(
    const float* x, const float* gamma, const float* beta, __bf16* hnT,
    const float* wq, __bf16* wq_bf, const float* wp, __bf16* wp_bf) {
    __shared__ __align__(16) char smem[32768];
    for (int rep = 0; rep < REPS; ++rep) {
        __syncthreads();
        gn_phase(smem, blockIdx.x, threadIdx.x, x, gamma, beta, hnT, wq, wq_bf, wp, wp_bf);
    }
}
__global__ __launch_bounds__(256, 2) void qkv_k(
    const __bf16* hnT, const __bf16* wq, const float* bq,
    __bf16* qkT, __bf16* vbuf, float qscale) {
    __shared__ __align__(16) char smem[65536];
    for (int rep = 0; rep < REPS; ++rep) {
        __syncthreads();
        qkv_tile(smem, blockIdx.x, threadIdx.x, hnT, wq, bq, qkT, vbuf, qscale);
    }
}
__global__ __launch_bounds__(256, 2) void attn_k(
    const __bf16* qkT, const __bf16* vbuf, __bf16* attnT) {
    __shared__ __align__(16) char smem[65536];
    for (int rep = 0; rep < REPS; ++rep) {
        __syncthreads();
        attn_unit(smem, blockIdx.x, threadIdx.x, qkT, vbuf, attnT);
    }
}
__global__ __launch_bounds__(256, 2) void proj_k(
    const __bf16* wp, const __bf16* attnT, const float* bp,
    const float* resid, float* out) {
    __shared__ __align__(16) char smem[49152];
    for (int rep = 0; rep < REPS; ++rep) {
        __syncthreads();
        proj_unit(smem, blockIdx.x, threadIdx.x, wp, attnT, bp, resid, out);
    }
}

extern "C" void kernel_launch(void* const* d_in, const int* in_sizes, int n_in,
                              void* d_out, int out_size, void* d_ws, size_t ws_size,
                              hipStream_t stream) {
    const float* x      = (const float*)d_in[0];
    const float* gamma  = (const float*)d_in[1];
    const float* beta   = (const float*)d_in[2];
    const float* w_qkv  = (const float*)d_in[3];
    const float* b_qkv  = (const float*)d_in[4];
    const float* w_proj = (const float*)d_in[5];
    const float* b_proj = (const float*)d_in[6];
    float* out = (float*)d_out;

    __bf16* wq_bf  = (__bf16*)d_ws;
    __bf16* wp_bf  = wq_bf + (size_t)1536 * 512;
    __bf16* hnT    = wp_bf + (size_t)512 * 512;
    __bf16* qkT    = hnT + (size_t)Bn * HW * Cc;
    __bf16* vbuf   = qkT + (size_t)Bn * HW * 1024;
    __bf16* attnT  = vbuf + (size_t)Bn * Cc * HW;

    float qscale = 0.125f * 1.44269504088896f;   // hd^-0.5 * log2(e)

    gn_k<<<768, 256, 0, stream>>>(x, gamma, beta, hnT, w_qkv, wq_bf, w_proj, wp_bf);
    qkv_k<<<768, 256, 0, stream>>>(hnT, wq_bf, b_qkv, qkT, vbuf, qscale);
    attn_k<<<512, 256, 0, stream>>>(qkT, vbuf, attnT);
    proj_k<<<512, 256, 0, stream>>>(wp_bf, attnT, b_proj, x, out);
}

// Round 9
// 139.054 us; speedup vs baseline: 1.8437x; 1.8437x over previous
//
#include <hip/hip_runtime.h>
#include <math.h>

#define Bn 8
#define Cc 512
#define HW 1024
#define HEADS 8
#define HD 64
#define GROUPS 32
#define CPG 16
#define EPS 1e-5f

// Counted-wait primitives (T3/T4): loads stay in flight across barriers.
#define VMW8()  asm volatile("s_waitcnt vmcnt(8)" ::: "memory")
#define VMW6()  asm volatile("s_waitcnt vmcnt(6)" ::: "memory")
#define VMW4()  asm volatile("s_waitcnt vmcnt(4)" ::: "memory")
#define VMW0()  asm volatile("s_waitcnt vmcnt(0)" ::: "memory")
#define LGKM0() asm volatile("s_waitcnt lgkmcnt(0)" ::: "memory")
#define SB()    __builtin_amdgcn_s_barrier()
#define SCHED0() __builtin_amdgcn_sched_barrier(0)

typedef float f32x4 __attribute__((ext_vector_type(4)));
typedef __bf16 bf16x8 __attribute__((ext_vector_type(8)));
typedef __bf16 bf16x4 __attribute__((ext_vector_type(4)));
typedef short s16x4 __attribute__((ext_vector_type(4)));
typedef unsigned u32x2 __attribute__((ext_vector_type(2)));

__device__ __forceinline__ void async16(const __bf16* g, __bf16* l) {
    __builtin_amdgcn_global_load_lds((const __attribute__((address_space(1))) unsigned int*)g,
                                     (__attribute__((address_space(3))) unsigned int*)l, 16, 0, 0);
}

__device__ __forceinline__ f32x4 mfma16(bf16x4 a, bf16x4 b, f32x4 c) {
    return __builtin_amdgcn_mfma_f32_16x16x16bf16_1k(
        __builtin_bit_cast(s16x4, a), __builtin_bit_cast(s16x4, b), c, 0, 0, 0);
}

__device__ __forceinline__ unsigned pk_bf16(float f1, float f0) {
    return __builtin_amdgcn_perm(__builtin_bit_cast(unsigned, f1),
                                 __builtin_bit_cast(unsigned, f0), 0x07060302u);
}

// ---------------- Phase 1: GN (blk<256) + weight conv (blk in [256,768)) ----------------
__device__ __forceinline__ void gn_phase(char* smem, int blk, int tid,
    const float* __restrict__ x, const float* __restrict__ gamma,
    const float* __restrict__ beta, __bf16* __restrict__ hnT,
    const float* __restrict__ wq, __bf16* __restrict__ wq_bf,
    const float* __restrict__ wp, __bf16* __restrict__ wp_bf) {
    if (blk >= 256) {
        int base = (blk - 256) * 512 + tid;
        #pragma unroll
        for (int u = 0; u < 2; ++u) {
            int i = base + u * 256;
            if (i < 196608) {
                float4 v = ((const float4*)wq)[i];
                bf16x4 o = { (__bf16)v.x, (__bf16)v.y, (__bf16)v.z, (__bf16)v.w };
                ((bf16x4*)wq_bf)[i] = o;
            } else {
                int j = i - 196608;
                float4 v = ((const float4*)wp)[j];
                bf16x4 o = { (__bf16)v.x, (__bf16)v.y, (__bf16)v.z, (__bf16)v.w };
                ((bf16x4*)wp_bf)[j] = o;
            }
        }
        return;
    }
    __bf16* xs = (__bf16*)smem;          // full 32 KB
    float* fs = (float*)smem;            // overlay: fs[0..9] used transiently
    int b = blk >> 5, g = blk & 31;
    const float* xp = x + ((size_t)b * Cc + g * CPG) * HW;

    float s = 0.f, ss = 0.f;
    for (int i4 = tid; i4 < 4096; i4 += 256) {
        float4 v = ((const float4*)xp)[i4];
        s  += (v.x + v.y) + (v.z + v.w);
        ss += (v.x * v.x + v.y * v.y) + (v.z * v.z + v.w * v.w);
        bf16x4 o = { (__bf16)v.x, (__bf16)v.y, (__bf16)v.z, (__bf16)v.w };
        ((bf16x4*)xs)[i4] = o;
    }
    for (int off = 32; off > 0; off >>= 1) {
        s  += __shfl_down(s, off);
        ss += __shfl_down(ss, off);
    }
    int wave = tid >> 6, lane = tid & 63;
    __syncthreads();                      // staging complete
    float keep = 0.f;
    if (tid < 20) keep = (float)xs[tid];  // preserve c=0, n=0..19 (lossless bf16 round-trip)
    __syncthreads();                      // reads done before overlay write
    if (lane == 0) { fs[wave * 2] = s; fs[wave * 2 + 1] = ss; }
    __syncthreads();
    if (tid == 0) {
        float S  = fs[0] + fs[2] + fs[4] + fs[6];
        float SS = fs[1] + fs[3] + fs[5] + fs[7];
        float mean = S / 16384.f;
        float var  = SS / 16384.f - mean * mean;
        fs[8] = mean;
        fs[9] = rsqrtf(var + EPS);
    }
    __syncthreads();
    float mean = fs[8], rstd = fs[9];
    __syncthreads();                      // all read stats before restore
    if (tid < 20) xs[tid] = (__bf16)keep; // restore xs
    __syncthreads();

    float gl[16], bl[16];                 // uniform -> scalar loads
    #pragma unroll
    for (int c = 0; c < 16; ++c) { gl[c] = gamma[g * CPG + c]; bl[c] = beta[g * CPG + c]; }
    #pragma unroll
    for (int u = 0; u < 4; ++u) {
        int n = tid + u * 256;
        union { __bf16 bs[16]; uint4 q[2]; } o;
        #pragma unroll
        for (int c = 0; c < 16; ++c) {
            float v = (float)xs[c * 1024 + n];
            o.bs[c] = (__bf16)((v - mean) * rstd * gl[c] + bl[c]);
        }
        uint4* dst = (uint4*)(hnT + ((size_t)b * HW + n) * Cc + g * CPG);
        dst[0] = o.q[0];
        dst[1] = o.q[1];
    }
}

// ---------------- Phase 2: one 128x128 QKV tile, counted-vmcnt pipeline ----------------
__device__ __forceinline__ void qkv_stage(char* base, int tid,
    const __bf16* __restrict__ Pb, const __bf16* __restrict__ Qb,
    int bm, int bn, int k0) {
    __bf16* As = (__bf16*)base;
    __bf16* Bs = (__bf16*)(base + 16384);
    #pragma unroll
    for (int u = 0; u < 4; ++u) {
        int idx = u * 256 + tid;
        int r = idx >> 3, lc = idx & 7;
        int cg2 = lc ^ (r & 7);
        async16(Pb + (size_t)(bm + r) * 512 + k0 + cg2 * 8, &As[idx * 8]);
        async16(Qb + (size_t)(bn + r) * 512 + k0 + cg2 * 8, &Bs[idx * 8]);
    }
}

__device__ __forceinline__ void qkv_tile(char* smem, int t, int tid,
    const __bf16* __restrict__ hnT, const __bf16* __restrict__ wq,
    const float* __restrict__ bias, __bf16* __restrict__ qkT,
    __bf16* __restrict__ vbuf, float scaleLo) {
    int wv = tid >> 6, lane = tid & 63, ln = lane & 15, quad = lane >> 4;
    int b = t / 96, rem = t % 96;
    int y = rem >> 3, xv = rem & 7;
    bool isQK = y < 8;
    int bm = (isQK ? y : y - 8) * 128;
    int bn = xv * 128;
    const __bf16* hb = hnT + (size_t)b * HW * Cc;
    const __bf16* Pb = isQK ? hb : wq + (size_t)1024 * 512;
    const __bf16* Qb = isQK ? wq : hb;
    int wm = (wv >> 1) * 64, wn = (wv & 1) * 64;

    f32x4 acc[4][4];
    #pragma unroll
    for (int i = 0; i < 4; ++i)
        #pragma unroll
        for (int j = 0; j < 4; ++j) acc[i][j] = (f32x4){0.f, 0.f, 0.f, 0.f};

    char* sm_cur = smem;
    char* sm_nxt = smem + 32768;

    qkv_stage(sm_cur, tid, Pb, Qb, bm, bn, 0);       // prologue: 8 loads/thread in flight

    for (int kt = 0; kt < 8; ++kt) {
        if (kt < 7) {
            qkv_stage(sm_nxt, tid, Pb, Qb, bm, bn, (kt + 1) * 64);  // +8 loads (next tile)
            VMW8();                                   // wait CUR's 8 (older); NXT's 8 stay in flight
        } else {
            VMW0();
        }
        SB(); SCHED0();                               // all waves: cur tile resident

        __bf16* As = (__bf16*)sm_cur;
        __bf16* Bs = (__bf16*)(sm_cur + 16384);
        bf16x8 af[4][2], bff[4][2];
        #pragma unroll
        for (int mt = 0; mt < 4; ++mt) {
            int row = wm + mt * 16 + ln;
            #pragma unroll
            for (int h = 0; h < 2; ++h) {
                int cc = (h * 4 + quad) ^ (ln & 7);
                af[mt][h] = *(const bf16x8*)&As[row * 64 + cc * 8];
            }
        }
        #pragma unroll
        for (int nt = 0; nt < 4; ++nt) {
            int row = wn + nt * 16 + ln;
            #pragma unroll
            for (int h = 0; h < 2; ++h) {
                int cc = (h * 4 + quad) ^ (ln & 7);
                bff[nt][h] = *(const bf16x8*)&Bs[row * 64 + cc * 8];
            }
        }
        #pragma unroll
        for (int mt = 0; mt < 4; ++mt)
            #pragma unroll
            for (int nt = 0; nt < 4; ++nt) {
                acc[mt][nt] = __builtin_amdgcn_mfma_f32_16x16x32_bf16(af[mt][0], bff[nt][0], acc[mt][nt], 0, 0, 0);
                acc[mt][nt] = __builtin_amdgcn_mfma_f32_16x16x32_bf16(af[mt][1], bff[nt][1], acc[mt][nt], 0, 0, 0);
            }
        if (kt < 7) {
            LGKM0(); SB(); SCHED0();                  // all reads of cur done -> overwrite ok
        }
        char* tmp = sm_cur; sm_cur = sm_nxt; sm_nxt = tmp;
    }

    if (isQK) {
        __bf16* out = qkT + (size_t)b * HW * 1024;
        float bcol[4], scol[4];
        #pragma unroll
        for (int nt = 0; nt < 4; ++nt) {
            int col = bn + wn + nt * 16 + ln;
            bcol[nt] = bias[col];
            scol[nt] = (col < 512) ? scaleLo : 1.0f;
        }
        #pragma unroll
        for (int mt = 0; mt < 4; ++mt)
            #pragma unroll
            for (int r = 0; r < 4; ++r) {
                int row = bm + wm + mt * 16 + quad * 4 + r;
                #pragma unroll
                for (int nt = 0; nt < 4; ++nt) {
                    int col = bn + wn + nt * 16 + ln;
                    out[(size_t)row * 1024 + col] = (__bf16)((acc[mt][nt][r] + bcol[nt]) * scol[nt]);
                }
            }
    } else {
        __bf16* out = vbuf + (size_t)b * Cc * HW;
        #pragma unroll
        for (int mt = 0; mt < 4; ++mt)
            #pragma unroll
            for (int r = 0; r < 4; ++r) {
                int row = bm + wm + mt * 16 + quad * 4 + r;
                float brow = bias[1024 + row];
                #pragma unroll
                for (int nt = 0; nt < 4; ++nt) {
                    int col = bn + wn + nt * 16 + ln;
                    out[(size_t)row * 1024 + col] = (__bf16)(acc[mt][nt][r] + brow);
                }
            }
    }
}

// ---------------- Phase 3: flash attention, QBLK=256 (512 thr), counted-vmcnt ------------
// K/V staged once per 256 q-rows instead of per 128: staging traffic halved (134->67 MB).
// Per-wave compute identical to previous verified version (each wave owns 32 q-rows).
__device__ __forceinline__ void attn_stage(char* base, int tid,
    const __bf16* __restrict__ qkT, const __bf16* __restrict__ vbuf,
    int b, int h, int kt) {
    __bf16* Ks = (__bf16*)base;
    __bf16* Vs = (__bf16*)(base + 16384);
    #pragma unroll
    for (int hh = 0; hh < 2; ++hh) {
        int kb = kt * 128 + hh * 64;
        int idx = tid;                    // 512 threads cover 512 idx slots
        int r = idx >> 3, lc = idx & 7;
        int cg2 = lc ^ (r & 7);
        async16(qkT + ((size_t)b * HW + kb + r) * 1024 + 512 + h * HD + cg2 * 8,
                &Ks[hh * 4096 + idx * 8]);
        async16(vbuf + ((size_t)b * Cc + h * HD + r) * HW + kb + cg2 * 8,
                &Vs[hh * 4096 + idx * 8]);
    }
}

__device__ __forceinline__ void attn_unit(char* smem, int blk, int tid,
    const __bf16* __restrict__ qkT, const __bf16* __restrict__ vbuf,
    __bf16* __restrict__ attnT) {
    int wv = tid >> 6, lane = tid & 63, ln = lane & 15, quad = lane >> 4;
    int h = blk & 7, qb = (blk >> 3) & 3, b = blk >> 5;   // grid 256 = 8b*4qb*8h
    int i0 = qb * 256 + wv * 32;                          // 8 waves x 32 q-rows

    const __bf16* qbase = qkT + ((size_t)b * HW + i0 + ln) * 1024 + h * HD + quad * 8;
    bf16x8 qf[2][2];
    #pragma unroll
    for (int mt = 0; mt < 2; ++mt) {
        qf[mt][0] = *(const bf16x8*)(qbase + (size_t)mt * 16 * 1024);
        qf[mt][1] = *(const bf16x8*)(qbase + (size_t)mt * 16 * 1024 + 32);
    }

    f32x4 oacc[2][4];
    #pragma unroll
    for (int mt = 0; mt < 2; ++mt)
        #pragma unroll
        for (int ct = 0; ct < 4; ++ct) oacc[mt][ct] = (f32x4){0.f, 0.f, 0.f, 0.f};
    float lsum[2] = {0.f, 0.f};

    char* sm_cur = smem;
    char* sm_nxt = smem + 32768;
    attn_stage(sm_cur, tid, qkT, vbuf, b, h, 0);     // prologue: 4 loads/thread

    for (int kt = 0; kt < 8; ++kt) {
        if (kt < 7) {
            attn_stage(sm_nxt, tid, qkT, vbuf, b, h, kt + 1);   // +4 loads
            VMW4();
        } else {
            VMW0();
        }
        SB(); SCHED0();

        __bf16* Ks = (__bf16*)sm_cur;
        __bf16* Vs = (__bf16*)(sm_cur + 16384);

        #pragma unroll
        for (int hh = 0; hh < 2; ++hh) {
            f32x4 st[2][4];
            #pragma unroll
            for (int jt = 0; jt < 4; ++jt) {
                int row = jt * 16 + ln;
                int c0 = quad ^ (ln & 7);
                int c1 = (4 + quad) ^ (ln & 7);
                bf16x8 kf0 = *(const bf16x8*)&Ks[hh * 4096 + row * 64 + c0 * 8];
                bf16x8 kf1 = *(const bf16x8*)&Ks[hh * 4096 + row * 64 + c1 * 8];
                #pragma unroll
                for (int mt = 0; mt < 2; ++mt) {
                    f32x4 s = (f32x4){0.f, 0.f, 0.f, 0.f};
                    s = __builtin_amdgcn_mfma_f32_16x16x32_bf16(kf0, qf[mt][0], s, 0, 0, 0);
                    s = __builtin_amdgcn_mfma_f32_16x16x32_bf16(kf1, qf[mt][1], s, 0, 0, 0);
                    st[mt][jt] = s;
                }
            }

            bf16x4 pk[2][4];
            #pragma unroll
            for (int mt = 0; mt < 2; ++mt)
                #pragma unroll
                for (int jt = 0; jt < 4; ++jt) {
                    float p0 = __builtin_amdgcn_exp2f(st[mt][jt][0]);
                    float p1 = __builtin_amdgcn_exp2f(st[mt][jt][1]);
                    float p2 = __builtin_amdgcn_exp2f(st[mt][jt][2]);
                    float p3 = __builtin_amdgcn_exp2f(st[mt][jt][3]);
                    lsum[mt] += (p0 + p1) + (p2 + p3);
                    u32x2 w = { pk_bf16(p1, p0), pk_bf16(p3, p2) };
                    pk[mt][jt] = __builtin_bit_cast(bf16x4, w);
                }

            #pragma unroll
            for (int ct = 0; ct < 4; ++ct) {
                int row = ct * 16 + ln;
                bf16x4 vf[4];
                #pragma unroll
                for (int kss = 0; kss < 4; ++kss) {
                    int cc16 = (kss * 2 + (quad >> 1)) ^ (ln & 7);
                    vf[kss] = *(const bf16x4*)&Vs[hh * 4096 + row * 64 + cc16 * 8 + (quad & 1) * 4];
                }
                #pragma unroll
                for (int mt = 0; mt < 2; ++mt)
                    #pragma unroll
                    for (int kss = 0; kss < 4; ++kss)
                        oacc[mt][ct] = mfma16(vf[kss], pk[mt][kss], oacc[mt][ct]);
            }
        }
        if (kt < 7) {
            LGKM0(); SB(); SCHED0();
        }
        char* tmp = sm_cur; sm_cur = sm_nxt; sm_nxt = tmp;
    }

    #pragma unroll
    for (int mt = 0; mt < 2; ++mt) {
        lsum[mt] += __shfl_xor(lsum[mt], 16);
        lsum[mt] += __shfl_xor(lsum[mt], 32);
        float rl = 1.f / lsum[mt];
        __bf16* op = attnT + ((size_t)b * HW + i0 + mt * 16 + ln) * Cc + h * HD + quad * 4;
        #pragma unroll
        for (int ct = 0; ct < 4; ++ct) {
            bf16x4 o = { (__bf16)(oacc[mt][ct][0] * rl), (__bf16)(oacc[mt][ct][1] * rl),
                         (__bf16)(oacc[mt][ct][2] * rl), (__bf16)(oacc[mt][ct][3] * rl) };
            *(bf16x4*)(op + ct * 16) = o;
        }
    }
}

// ---------------- Phase 4: proj 64x128 tile, counted-vmcnt pipeline ----------------
__device__ __forceinline__ void proj_stage(char* base, int tid,
    const __bf16* __restrict__ wp, const __bf16* __restrict__ Qb,
    int bm, int bn, int k0) {
    __bf16* As = (__bf16*)base;
    __bf16* Bs = (__bf16*)(base + 8192);
    #pragma unroll
    for (int u = 0; u < 2; ++u) {
        int idx = u * 256 + tid;
        int r = idx >> 3, lc = idx & 7;
        int cg2 = lc ^ (r & 7);
        async16(wp + (size_t)(bm + r) * 512 + k0 + cg2 * 8, &As[idx * 8]);
    }
    #pragma unroll
    for (int u = 0; u < 4; ++u) {
        int idx = u * 256 + tid;
        int r = idx >> 3, lc = idx & 7;
        int cg2 = lc ^ (r & 7);
        async16(Qb + (size_t)(bn + r) * 512 + k0 + cg2 * 8, &Bs[idx * 8]);
    }
}

__device__ __forceinline__ void proj_unit(char* smem, int blk, int tid,
    const __bf16* __restrict__ wp, const __bf16* __restrict__ attnT,
    const float* __restrict__ bias, const float* __restrict__ resid,
    float* __restrict__ outp) {
    int wv = tid >> 6, lane = tid & 63, ln = lane & 15, quad = lane >> 4;
    int xv = blk & 7, y = (blk >> 3) & 7, b = blk >> 6;
    int bm = y * 64, bn = xv * 128;
    const __bf16* Qb = attnT + (size_t)b * HW * Cc;
    int wm = (wv >> 1) * 32, wn = (wv & 1) * 64;

    f32x4 acc[2][4];
    #pragma unroll
    for (int i = 0; i < 2; ++i)
        #pragma unroll
        for (int j = 0; j < 4; ++j) acc[i][j] = (f32x4){0.f, 0.f, 0.f, 0.f};

    char* sm_cur = smem;
    char* sm_nxt = smem + 24576;
    proj_stage(sm_cur, tid, wp, Qb, bm, bn, 0);      // prologue: 6 loads/thread

    for (int kt = 0; kt < 8; ++kt) {
        if (kt < 7) {
            proj_stage(sm_nxt, tid, wp, Qb, bm, bn, (kt + 1) * 64);  // +6 loads
            VMW6();
        } else {
            VMW0();
        }
        SB(); SCHED0();

        __bf16* As = (__bf16*)sm_cur;
        __bf16* Bs = (__bf16*)(sm_cur + 8192);
        bf16x8 af[2][2], bff[4][2];
        #pragma unroll
        for (int mt = 0; mt < 2; ++mt) {
            int row = wm + mt * 16 + ln;
            #pragma unroll
            for (int h = 0; h < 2; ++h) {
                int cc = (h * 4 + quad) ^ (ln & 7);
                af[mt][h] = *(const bf16x8*)&As[row * 64 + cc * 8];
            }
        }
        #pragma unroll
        for (int nt = 0; nt < 4; ++nt) {
            int row = wn + nt * 16 + ln;
            #pragma unroll
            for (int h = 0; h < 2; ++h) {
                int cc = (h * 4 + quad) ^ (ln & 7);
                bff[nt][h] = *(const bf16x8*)&Bs[row * 64 + cc * 8];
            }
        }
        #pragma unroll
        for (int mt = 0; mt < 2; ++mt)
            #pragma unroll
            for (int nt = 0; nt < 4; ++nt) {
                acc[mt][nt] = __builtin_amdgcn_mfma_f32_16x16x32_bf16(af[mt][0], bff[nt][0], acc[mt][nt], 0, 0, 0);
                acc[mt][nt] = __builtin_amdgcn_mfma_f32_16x16x32_bf16(af[mt][1], bff[nt][1], acc[mt][nt], 0, 0, 0);
            }
        if (kt < 7) {
            LGKM0(); SB(); SCHED0();
        }
        char* tmp = sm_cur; sm_cur = sm_nxt; sm_nxt = tmp;
    }

    float* out = outp + (size_t)b * Cc * HW;
    const float* res = resid + (size_t)b * Cc * HW;
    #pragma unroll
    for (int mt = 0; mt < 2; ++mt)
        #pragma unroll
        for (int r = 0; r < 4; ++r) {
            int row = bm + wm + mt * 16 + quad * 4 + r;
            float bv = bias[row];
            #pragma unroll
            for (int nt = 0; nt < 4; ++nt) {
                int col = bn + wn + nt * 16 + ln;
                size_t idx = (size_t)row * 1024 + col;
                out[idx] = acc[mt][nt][r] + bv + res[idx];
            }
        }
}

// ---------------- Phase kernels (4 regular launches) ----------------
__global__ __launch_bounds__(256, 3) void gn_k(
    const float* x, const float* gamma, const float* beta, __bf16* hnT,
    const float* wq, __bf16* wq_bf, const float* wp, __bf16* wp_bf) {
    __shared__ __align__(16) char smem[32768];
    gn_phase(smem, blockIdx.x, threadIdx.x, x, gamma, beta, hnT, wq, wq_bf, wp, wp_bf);
}
__global__ __launch_bounds__(256, 2) void qkv_k(
    const __bf16* hnT, const __bf16* wq, const float* bq,
    __bf16* qkT, __bf16* vbuf, float qscale) {
    __shared__ __align__(16) char smem[65536];
    qkv_tile(smem, blockIdx.x, threadIdx.x, hnT, wq, bq, qkT, vbuf, qscale);
}
__global__ __launch_bounds__(512, 2) void attn_k(
    const __bf16* qkT, const __bf16* vbuf, __bf16* attnT) {
    __shared__ __align__(16) char smem[65536];
    attn_unit(smem, blockIdx.x, threadIdx.x, qkT, vbuf, attnT);
}
__global__ __launch_bounds__(256, 2) void proj_k(
    const __bf16* wp, const __bf16* attnT, const float* bp,
    const float* resid, float* out) {
    __shared__ __align__(16) char smem[49152];
    proj_unit(smem, blockIdx.x, threadIdx.x, wp, attnT, bp, resid, out);
}

extern "C" void kernel_launch(void* const* d_in, const int* in_sizes, int n_in,
                              void* d_out, int out_size, void* d_ws, size_t ws_size,
                              hipStream_t stream) {
    const float* x      = (const float*)d_in[0];
    const float* gamma  = (const float*)d_in[1];
    const float* beta   = (const float*)d_in[2];
    const float* w_qkv  = (const float*)d_in[3];
    const float* b_qkv  = (const float*)d_in[4];
    const float* w_proj = (const float*)d_in[5];
    const float* b_proj = (const float*)d_in[6];
    float* out = (float*)d_out;

    __bf16* wq_bf  = (__bf16*)d_ws;
    __bf16* wp_bf  = wq_bf + (size_t)1536 * 512;
    __bf16* hnT    = wp_bf + (size_t)512 * 512;
    __bf16* qkT    = hnT + (size_t)Bn * HW * Cc;
    __bf16* vbuf   = qkT + (size_t)Bn * HW * 1024;
    __bf16* attnT  = vbuf + (size_t)Bn * Cc * HW;

    float qscale = 0.125f * 1.44269504088896f;   // hd^-0.5 * log2(e)

    gn_k<<<768, 256, 0, stream>>>(x, gamma, beta, hnT, w_qkv, wq_bf, w_proj, wp_bf);
    qkv_k<<<768, 256, 0, stream>>>(hnT, wq_bf, b_qkv, qkT, vbuf, qscale);
    attn_k<<<256, 512, 0, stream>>>(qkT, vbuf, attnT);
    proj_k<<<512, 256, 0, stream>>>(wp_bf, attnT, b_proj, x, out);
}